// Round 9
// baseline (236.492 us; speedup 1.0000x reference)
//
#include <hip/hip_runtime.h>

typedef __bf16 bf16x8_t __attribute__((ext_vector_type(8)));
typedef float f32x16_t __attribute__((ext_vector_type(16)));
typedef unsigned short ushort_t;

__device__ __forceinline__ unsigned short f2bf(float f) {
  unsigned u = __float_as_uint(f);
  u = (u + 0x7FFFu + ((u >> 16) & 1u)) >> 16;
  return (unsigned short)u;
}
__device__ __forceinline__ float bf2f(unsigned short h) {
  return __uint_as_float(((unsigned)h) << 16);
}

// async global->LDS, 16B/lane. LDS dest = wave-uniform base + lane*16.
__device__ __forceinline__ void gload16(const void* g, void* l) {
  __builtin_amdgcn_global_load_lds(
      (const __attribute__((address_space(1))) unsigned int*)g,
      (__attribute__((address_space(3))) unsigned int*)l, 16, 0, 0);
}

// ===========================================================================
// (64*MFR)x128 NT GEMM, mfma_f32_32x32x16_bf16, r7-proven 2-buffer loop
// (stage(t+1) at top, one __syncthreads per K-tile; 4-5+ blocks/CU TLP).
// MFR=2: 128x128, 32KB LDS, acc 64 AGPR, bounds(256,4)  [QKV projections]
// MFR=1:  64x128, 24KB LDS, acc 32 AGPR, bounds(256,6)  [S, PV: 2x occupancy]
// Swizzle g(row)=(row>>1)&3 both sides (src-preswizzled global + XOR ds_read).
// A-select: tile col bn >= nsplit ? A2 : A  (merges x- and y-sourced gemms).
// EPI: 0 plain(+bias) | 1 exp()+row-partial-sums (softmax fused) | 2 row*aux.
// C/D 32x32: col=lane&31, row=(reg&3)+8*(reg>>2)+4*(lane>>5)  [m74/m101]
// ===========================================================================
template<int MFR, int EPI, bool OUT_BF16, bool HAS_BIAS>
__global__ __launch_bounds__(256, (MFR == 2 ? 4 : 6))
void gemm32(const ushort_t* __restrict__ A, const ushort_t* __restrict__ A2,
            int nsplit, const ushort_t* __restrict__ Bt,
            void* __restrict__ Cp, const float* __restrict__ bias,
            float* __restrict__ aux,
            int gx, int gy, int K, int lda, int ldb, int ldc,
            long sA, long sB, long sC, float alpha)
{
  constexpr int ATILE = 2048 * MFR;          // ushorts per A buf
  constexpr int BUFSZ = ATILE + 4096;
  __shared__ __align__(16) ushort_t sm[2 * BUFSZ];
  const int tid = threadIdx.x;
  const int lane = tid & 63;
  const int w = tid >> 6;
  const int wr = w >> 1, wc = w & 1;

  // bijective XCD-chunked swizzle (grids %8==0)
  const int per = gridDim.x >> 3;
  int wg = blockIdx.x;
  wg = (wg & 7) * per + (wg >> 3);
  const int bz = wg / (gx * gy);
  const int rr = wg - bz * gx * gy;
  const int by = rr / gx, bx = rr - by * gx;
  const int bm = by * (64 * MFR), bn = bx * 128;

  const ushort_t* Ab = (bn >= nsplit) ? A2 : A;

  // staging ptrs (source pre-swizzled). A: MFR slots/wave, B: 2 slots/wave.
  const int rA0 = (w * MFR) * 16 + (lane >> 2);
  const int cswA = (((lane & 3) ^ ((rA0 >> 1) & 3)) << 3);
  const int rB0 = (w * 2) * 16 + (lane >> 2);
  const int cswB = (((lane & 3) ^ ((rB0 >> 1) & 3)) << 3);
  const ushort_t* pA0 = Ab + (long)bz * sA + (long)(bm + rA0) * lda + cswA;
  const ushort_t* pB0 = Bt + (long)bz * sB + (long)(bn + rB0) * ldb + cswB;

  auto stage = [&](int kt, int buf) {
    const int k0 = kt << 5;
    ushort_t* s = sm + buf * BUFSZ;
#pragma unroll
    for (int i = 0; i < MFR; ++i)
      gload16(pA0 + i * 16 * lda + k0, s + (w * MFR + i) * 512);
#pragma unroll
    for (int i = 0; i < 2; ++i)
      gload16(pB0 + i * 16 * ldb + k0, s + ATILE + (w * 2 + i) * 512);
  };

  // fragment ds_read offsets
  const int l31 = lane & 31, kh = lane >> 5;
  int offA[MFR][2], offB[2][2];
#pragma unroll
  for (int m = 0; m < MFR; ++m) {
    const int row = wr * (32 * MFR) + m * 32 + l31;
#pragma unroll
    for (int s = 0; s < 2; ++s)
      offA[m][s] = row * 32 + (((s * 2 + kh) ^ ((row >> 1) & 3)) << 3);
  }
#pragma unroll
  for (int n = 0; n < 2; ++n) {
    const int row = wc * 64 + n * 32 + l31;
#pragma unroll
    for (int s = 0; s < 2; ++s)
      offB[n][s] = ATILE + row * 32 + (((s * 2 + kh) ^ ((row >> 1) & 3)) << 3);
  }

  f32x16_t acc[MFR][2];
#pragma unroll
  for (int m = 0; m < MFR; ++m)
#pragma unroll
    for (int n = 0; n < 2; ++n)
#pragma unroll
      for (int i = 0; i < 16; ++i) acc[m][n][i] = 0.f;

  stage(0, 0);
  __syncthreads();

#define LDX(off) __builtin_bit_cast(bf16x8_t, *(const uint4*)(sp + (off)))
  const int nt = K >> 5;
  for (int kt = 0; kt < nt; ++kt) {
    const int cur = kt & 1;
    if (kt + 1 < nt) stage(kt + 1, cur ^ 1);   // in flight across MFMAs
    const ushort_t* sp = sm + cur * BUFSZ;
    bf16x8_t af[MFR][2], bf[2][2];
#pragma unroll
    for (int m = 0; m < MFR; ++m)
#pragma unroll
      for (int s = 0; s < 2; ++s) af[m][s] = LDX(offA[m][s]);
#pragma unroll
    for (int n = 0; n < 2; ++n)
#pragma unroll
      for (int s = 0; s < 2; ++s) bf[n][s] = LDX(offB[n][s]);
    __builtin_amdgcn_s_setprio(1);
#pragma unroll
    for (int s = 0; s < 2; ++s)
#pragma unroll
      for (int m = 0; m < MFR; ++m)
#pragma unroll
        for (int n = 0; n < 2; ++n)
          acc[m][n] = __builtin_amdgcn_mfma_f32_32x32x16_bf16(
              af[m][s], bf[n][s], acc[m][n], 0, 0, 0);
    __builtin_amdgcn_s_setprio(0);
    __syncthreads();
  }
#undef LDX

  // ---- epilogue ----
  const long zC = (long)bz * sC;
#pragma unroll
  for (int m = 0; m < MFR; ++m) {
    const int growb = bm + wr * (32 * MFR) + m * 32;
    float part[16];
    if constexpr (EPI == 1) {
#pragma unroll
      for (int r = 0; r < 16; ++r) part[r] = 0.f;
    }
#pragma unroll
    for (int n = 0; n < 2; ++n) {
      const int gcol = bn + wc * 64 + n * 32 + l31;
      float bv_ = 0.f;
      if constexpr (HAS_BIAS) bv_ = bias[gcol];
#pragma unroll
      for (int r = 0; r < 16; ++r) {
        const int grow = growb + (r & 3) + 8 * (r >> 2) + 4 * kh;
        float v = acc[m][n][r] * alpha + bv_;
        if constexpr (EPI == 1) {
          const ushort_t pb = f2bf(__expf(v));
          ((ushort_t*)Cp)[zC + (long)grow * ldc + gcol] = pb;
          part[r] += bf2f(pb);
        } else if constexpr (EPI == 2) {
          v *= aux[bz * 2048 + grow];
          ((float*)Cp)[zC + (long)grow * ldc + gcol] = v;
        } else if constexpr (OUT_BF16) {
          ((ushort_t*)Cp)[zC + (long)grow * ldc + gcol] = f2bf(v);
        } else {
          ((float*)Cp)[zC + (long)grow * ldc + gcol] = v;
        }
      }
    }
    if constexpr (EPI == 1) {
      // col-reduce over the 32-lane group (rows lane-invariant within it)
#pragma unroll
      for (int step = 1; step < 32; step <<= 1)
#pragma unroll
        for (int r = 0; r < 16; ++r) part[r] += __shfl_xor(part[r], step, 64);
      if (m == 0) {
        __syncthreads();
        float* pf = (float*)sm;
        if (tid < 64 * MFR) pf[tid] = 0.f;
        __syncthreads();
      }
      if (l31 == 0) {
        float* pf = (float*)sm;
#pragma unroll
        for (int r = 0; r < 16; ++r) {
          const int rloc = wr * (32 * MFR) + m * 32 + (r & 3) + 8 * (r >> 2) + 4 * kh;
          atomicAdd(&pf[rloc], part[r]);
        }
      }
    }
  }
  if constexpr (EPI == 1) {
    __syncthreads();
    if (tid < 64 * MFR) {
      const float* pf = (const float*)sm;
      aux[(long)bx * 8192 + bz * 2048 + by * (64 * MFR) + tid] = pf[tid];
    }
  }
}

// inv[r] = 1 / sum_k psumG[k][r],  16 col-chunks, 8192 rows
__global__ __launch_bounds__(256)
void invrow(const float* __restrict__ psumG, float* __restrict__ inv) {
  const int r = blockIdx.x * 256 + threadIdx.x;
  float s = 0.f;
#pragma unroll
  for (int k = 0; k < 16; ++k) s += psumG[(long)k * 8192 + r];
  inv[r] = 1.0f / s;
}

// fp32 -> bf16 bulk convert for x and y in one launch (8 elems/thread)
__global__ __launch_bounds__(256)
void conv2(const float* __restrict__ x, const float* __restrict__ y,
           ushort_t* __restrict__ xb, ushort_t* __restrict__ yb) {
  const int b = blockIdx.x;
  const float* in = (b < 4096) ? x : y;
  ushort_t* out = (b < 4096) ? xb : yb;
  const long i = (long)(b & 4095) * 256 + threadIdx.x;
  const float4 a = ((const float4*)in)[i * 2];
  const float4 c = ((const float4*)in)[i * 2 + 1];
  uint4 o;
  o.x = (unsigned)f2bf(a.x) | ((unsigned)f2bf(a.y) << 16);
  o.y = (unsigned)f2bf(a.z) | ((unsigned)f2bf(a.w) << 16);
  o.z = (unsigned)f2bf(c.x) | ((unsigned)f2bf(c.y) << 16);
  o.w = (unsigned)f2bf(c.z) | ((unsigned)f2bf(c.w) << 16);
  ((uint4*)out)[i] = o;
}

// Wt[n][k] = (bf16) W[k][n], D=1024, 3 weights -> contiguous [3072][1024]
__global__ __launch_bounds__(256)
void wtrans3(const float* __restrict__ W0, const float* __restrict__ W1,
             const float* __restrict__ W2, ushort_t* __restrict__ T0,
             ushort_t* __restrict__ T1, ushort_t* __restrict__ T2) {
  const float* W = (blockIdx.z == 0) ? W0 : (blockIdx.z == 1) ? W1 : W2;
  ushort_t* Wt = (blockIdx.z == 0) ? T0 : (blockIdx.z == 1) ? T1 : T2;
  __shared__ float tile[32][33];
  const int bx = blockIdx.x * 32;
  const int by = blockIdx.y * 32;
  const int t = threadIdx.x;
  const int c = t & 31, r0 = t >> 5;
#pragma unroll
  for (int i = 0; i < 4; ++i)
    tile[r0 + i * 8][c] = W[(long)(by + r0 + i * 8) * 1024 + bx + c];
  __syncthreads();
#pragma unroll
  for (int i = 0; i < 4; ++i)
    Wt[(long)(bx + r0 + i * 8) * 1024 + by + c] = f2bf(tile[c][r0 + i * 8]);
}

// bias3 = bq || bk || bv  [3072]
__global__ __launch_bounds__(256)
void bconcat3(const float* __restrict__ a, const float* __restrict__ b,
              const float* __restrict__ c, float* __restrict__ o) {
  const int i = blockIdx.x * 256 + threadIdx.x;
  o[i] = (i < 1024) ? a[i] : (i < 2048) ? b[i - 1024] : c[i - 2048];
}

// bf16 transpose with strides: out[c][r] = in[r][c], 64x64 tiles per batch
__global__ __launch_bounds__(256)
void transpose_bf16(const ushort_t* __restrict__ in, ushort_t* __restrict__ out,
                    int ld_in, int ld_out, long in_bs, long out_bs) {
  __shared__ ushort_t tt[64][65];
  in += (long)blockIdx.z * in_bs;
  out += (long)blockIdx.z * out_bs;
  const int r0 = blockIdx.y * 64, c0 = blockIdx.x * 64;
  const int tc = threadIdx.x & 31;
  const int tr = threadIdx.x >> 5;
#pragma unroll
  for (int i = 0; i < 8; ++i) {
    const unsigned v = *(const unsigned*)(in + (long)(r0 + tr + 8 * i) * ld_in + c0 + tc * 2);
    tt[tr + 8 * i][tc * 2] = (ushort_t)(v & 0xffff);
    tt[tr + 8 * i][tc * 2 + 1] = (ushort_t)(v >> 16);
  }
  __syncthreads();
#pragma unroll
  for (int i = 0; i < 8; ++i) {
    const unsigned v = (unsigned)tt[tc * 2][tr + 8 * i] |
                       ((unsigned)tt[tc * 2 + 1][tr + 8 * i] << 16);
    *(unsigned*)(out + (long)(c0 + tr + 8 * i) * ld_out + r0 + tc * 2) = v;
  }
}

extern "C" void kernel_launch(void* const* d_in, const int* in_sizes, int n_in,
                              void* d_out, int out_size, void* d_ws, size_t ws_size,
                              hipStream_t stream) {
  const float* x  = (const float*)d_in[0];
  const float* y  = (const float*)d_in[1];
  const float* Wq = (const float*)d_in[2];
  const float* bq = (const float*)d_in[3];
  const float* Wk = (const float*)d_in[4];
  const float* bk = (const float*)d_in[5];
  const float* Wv = (const float*)d_in[6];
  const float* bv = (const float*)d_in[7];
  float* out = (float*)d_out;

  const int D = 1024;
  const long MB_ = 1l << 20;

  // ws layout (ushort units):
  //  [0,3M)    Wall = Wq^T || Wk^T || Wv^T   [3072][1024] bf16
  //  [3M,27M)  QKV8 [8192][3072] bf16  (Q cols 0-1023, K 1024-2047, V 2048-)
  //  [27M,43M) Sb [B][2048][2048] bf16; pre-aliased: yb@27M, xb@35M
  //  [43M,51M) Vt [B][1024][2048] bf16
  //  [51M+)    bias3 [3072] f32, psumG [16][8192] f32, inv [8192] f32
  ushort_t* ws   = (ushort_t*)d_ws;
  ushort_t* Wall = ws;
  ushort_t* QKV8 = ws + 3 * MB_;
  ushort_t* Sb   = ws + 27 * MB_;
  ushort_t* yb   = ws + 27 * MB_;
  ushort_t* xb   = ws + 35 * MB_;
  ushort_t* Vt   = ws + 43 * MB_;
  float*    bias3 = (float*)(ws + 51 * MB_);
  float*    psumG = (float*)(ws + 51 * MB_ + 8192);
  float*    inv   = psumG + 16 * 8192;

  dim3 blk(256);

  conv2<<<dim3(8192), blk, 0, stream>>>(x, y, xb, yb);
  wtrans3<<<dim3(32, 32, 3), blk, 0, stream>>>(
      Wq, Wk, Wv, Wall, Wall + 1 * MB_, Wall + 2 * MB_);
  bconcat3<<<dim3(12), blk, 0, stream>>>(bq, bk, bv, bias3);

  // QKV8 = [xb|yb] @ Wall^T + bias3 -> [8192][3072]; grid 24x64 = 1536
  gemm32<2, 0, true, true><<<dim3(1536), blk, 0, stream>>>(
      xb, yb, 1024, Wall, QKV8, bias3, nullptr,
      24, 64, D, D, D, 3072, 0, 0, 0, 1.0f);

  // Vt[b][d][t] = QKV8[b*2048+t][2048+d]
  transpose_bf16<<<dim3(16, 32, 4), blk, 0, stream>>>(
      QKV8 + 2048, Vt, 3072, 2048, 2048l * 3072, 1024l * 2048);

  // P' = exp((Q K^T)/32) -> bf16 [B][2048][2048] + row partial sums
  // MFR=1: 64x128 tiles, grid 16x32x4 = 2048 (8/CU)
  gemm32<1, 1, true, false><<<dim3(2048), blk, 0, stream>>>(
      QKV8, QKV8, 1 << 30, QKV8 + 1024, Sb, nullptr, psumG,
      16, 32, D, 3072, 3072, 2048,
      2048l * 3072, 2048l * 3072, 2048l * 2048, 0.03125f);

  invrow<<<dim3(32), blk, 0, stream>>>(psumG, inv);

  // out = (P' @ V) * inv[row]; MFR=1: grid 8x32x4 = 1024 (4/CU)
  gemm32<1, 2, false, false><<<dim3(1024), blk, 0, stream>>>(
      Sb, Sb, 1 << 30, Vt, out, nullptr, inv,
      8, 32, 2048, 2048, 2048, D,
      2048l * 2048, 1024l * 2048, 2048l * 1024, 1.0f);
}

// Round 10
// 206.377 us; speedup vs baseline: 1.1459x; 1.1459x over previous
//
#include <hip/hip_runtime.h>

typedef __bf16 bf16x8_t __attribute__((ext_vector_type(8)));
typedef float f32x16_t __attribute__((ext_vector_type(16)));
typedef unsigned short ushort_t;

__device__ __forceinline__ unsigned short f2bf(float f) {
  unsigned u = __float_as_uint(f);
  u = (u + 0x7FFFu + ((u >> 16) & 1u)) >> 16;
  return (unsigned short)u;
}
__device__ __forceinline__ float bf2f(unsigned short h) {
  return __uint_as_float(((unsigned)h) << 16);
}

// async global->LDS, 16B/lane. LDS dest = wave-uniform base + lane*16.
__device__ __forceinline__ void gload16(const void* g, void* l) {
  __builtin_amdgcn_global_load_lds(
      (const __attribute__((address_space(1))) unsigned int*)g,
      (__attribute__((address_space(3))) unsigned int*)l, 16, 0, 0);
}

// ===========================================================================
// gemm_big: 256xBN NT GEMM, mfma_f32_32x32x16_bf16, 2-barrier r7 loop, but
// PER-WAVE TILE 128x64 (acc[4][2] = 128 AGPR) -> 32.8 FLOP/LDS-byte (vs 21.8
// for 64x64 waves). BN=256: 8 waves/512thr, LDS 64KB, 1 blk/CU. BN=128:
// 4 waves/256thr, LDS 48KB, 2 blk/CU.  BK=32 ([R][32] ushort tiles, 64B rows).
// Swizzle: LDS(row,chunk16B)=G(row,chunk^((row>>1)&3)); ds_read XORs same.
//   8 consecutive rows -> slots (row&1, chunk') cover all 32 banks; frag b128
//   reads land ~4-way (m201-level residual).
// EPI: 0 plain | 1 exp(alpha*acc)+row-partial-sums->aux | 2 scale by aux[row].
// C/D 32x32: col=lane&31, row=(reg&3)+8*(reg>>2)+4*(lane>>5)  [m74/m101]
// ===========================================================================
template<int BN, int EPI>
__global__ __launch_bounds__((BN / 64) * 128, 2)
void gemm_big(const ushort_t* __restrict__ A, const ushort_t* __restrict__ Bt,
              void* __restrict__ Cp, float* __restrict__ aux,
              int gx, int gy, int K, int lda, int ldb, int ldc,
              long sA, long sB, long sC, float alpha)
{
  constexpr int WC = BN / 64;            // wave-cols (2 rows x WC)
  constexpr int NW = 2 * WC;             // waves
  constexpr int BUFSZ = 8192 + BN * 32;  // ushorts: A[256][32] + B[BN][32]
  constexpr int A_SPW = 16 / NW;         // A staging slots per wave (1KB each)
  constexpr int B_SPW = (BN / 16) / NW;  // = 2
  __shared__ __align__(16) ushort_t sm[2 * BUFSZ];

  const int tid = threadIdx.x;
  const int lane = tid & 63;
  const int w = tid >> 6;
  const int wr = w / WC, wc = w % WC;

  // bijective XCD-chunked swizzle (grids %8==0)
  const int per = gridDim.x >> 3;
  int wg = blockIdx.x;
  wg = (wg & 7) * per + (wg >> 3);
  const int bz = wg / (gx * gy);
  const int rr = wg - bz * gx * gy;
  const int by = rr / gx, bx = rr - by * gx;
  const int bm = by * 256, bn = bx * BN;

  // staging (source pre-swizzled; csw constant across 16-row slots)
  const int csw = (((lane & 3) ^ ((lane >> 3) & 3)) << 3);  // elems
  const ushort_t* pA = A + (long)bz * sA +
      (long)(bm + w * (A_SPW * 16) + (lane >> 2)) * lda + csw;
  const ushort_t* pB = Bt + (long)bz * sB +
      (long)(bn + w * (B_SPW * 16) + (lane >> 2)) * ldb + csw;

  auto stage = [&](int kt, int buf) {
    const int k0 = kt << 5;
    ushort_t* s = sm + buf * BUFSZ;
#pragma unroll
    for (int i = 0; i < A_SPW; ++i)
      gload16(pA + (long)(i * 16) * lda + k0, s + (w * A_SPW + i) * 512);
#pragma unroll
    for (int i = 0; i < B_SPW; ++i)
      gload16(pB + (long)(i * 16) * ldb + k0, s + 8192 + (w * B_SPW + i) * 512);
  };

  // fragment ds_read offsets (ushort units within buf)
  const int l31 = lane & 31, kh = lane >> 5;
  const int sw3 = (lane >> 1) & 3;
  int offA[4][2], offB[2][2];
#pragma unroll
  for (int mf = 0; mf < 4; ++mf)
#pragma unroll
    for (int ks = 0; ks < 2; ++ks)
      offA[mf][ks] = (wr * 128 + mf * 32 + l31) * 32 +
                     (((ks * 2 + kh) ^ sw3) << 3);
#pragma unroll
  for (int nf = 0; nf < 2; ++nf)
#pragma unroll
    for (int ks = 0; ks < 2; ++ks)
      offB[nf][ks] = 8192 + (wc * 64 + nf * 32 + l31) * 32 +
                     (((ks * 2 + kh) ^ sw3) << 3);

  f32x16_t acc[4][2];
#pragma unroll
  for (int m = 0; m < 4; ++m)
#pragma unroll
    for (int n = 0; n < 2; ++n)
#pragma unroll
      for (int i = 0; i < 16; ++i) acc[m][n][i] = 0.f;

  stage(0, 0);
  __syncthreads();

#define LDX(off) __builtin_bit_cast(bf16x8_t, *(const uint4*)(sp + (off)))
  const int nt = K >> 5;
  for (int kt = 0; kt < nt; ++kt) {
    const int cur = kt & 1;
    if (kt + 1 < nt) stage(kt + 1, cur ^ 1);   // in flight across MFMAs
    const ushort_t* sp = sm + cur * BUFSZ;
    bf16x8_t af[4][2], bfv[2][2];
#pragma unroll
    for (int mf = 0; mf < 4; ++mf)
#pragma unroll
      for (int ks = 0; ks < 2; ++ks) af[mf][ks] = LDX(offA[mf][ks]);
#pragma unroll
    for (int nf = 0; nf < 2; ++nf)
#pragma unroll
      for (int ks = 0; ks < 2; ++ks) bfv[nf][ks] = LDX(offB[nf][ks]);
    __builtin_amdgcn_s_setprio(1);
#pragma unroll
    for (int ks = 0; ks < 2; ++ks)
#pragma unroll
      for (int mf = 0; mf < 4; ++mf)
#pragma unroll
        for (int nf = 0; nf < 2; ++nf)
          acc[mf][nf] = __builtin_amdgcn_mfma_f32_32x32x16_bf16(
              af[mf][ks], bfv[nf][ks], acc[mf][nf], 0, 0, 0);
    __builtin_amdgcn_s_setprio(0);
    __syncthreads();
  }
#undef LDX

  // ---- epilogue ----
  const long zC = (long)bz * sC;
  float* pf = (float*)sm;
  if constexpr (EPI == 1) {
    if (tid < 256) pf[tid] = 0.f;
    __syncthreads();
  }
#pragma unroll
  for (int mf = 0; mf < 4; ++mf) {
    const int growb = bm + wr * 128 + mf * 32;
    float part[16];
    if constexpr (EPI == 1) {
#pragma unroll
      for (int r = 0; r < 16; ++r) part[r] = 0.f;
    }
#pragma unroll
    for (int nf = 0; nf < 2; ++nf) {
      const int gcol = bn + wc * 64 + nf * 32 + l31;
#pragma unroll
      for (int r = 0; r < 16; ++r) {
        const int grow = growb + (r & 3) + 8 * (r >> 2) + 4 * kh;
        float v = acc[mf][nf][r] * alpha;
        if constexpr (EPI == 1) {
          const ushort_t pb = f2bf(__expf(v));
          ((ushort_t*)Cp)[zC + (long)grow * ldc + gcol] = pb;
          part[r] += bf2f(pb);
        } else if constexpr (EPI == 2) {
          v *= aux[bz * 2048 + grow];
          ((float*)Cp)[zC + (long)grow * ldc + gcol] = v;
        } else {
          ((ushort_t*)Cp)[zC + (long)grow * ldc + gcol] = f2bf(v);
        }
      }
    }
    if constexpr (EPI == 1) {
      // reduce across the 32-lane half (each half: same rows, 64 cols total)
#pragma unroll
      for (int step = 1; step < 32; step <<= 1)
#pragma unroll
        for (int r = 0; r < 16; ++r) part[r] += __shfl_xor(part[r], step, 64);
      if (l31 == 0) {
#pragma unroll
        for (int r = 0; r < 16; ++r) {
          const int rloc = wr * 128 + mf * 32 + (r & 3) + 8 * (r >> 2) + 4 * kh;
          atomicAdd(&pf[rloc], part[r]);
        }
      }
    }
  }
  if constexpr (EPI == 1) {
    __syncthreads();
    if (tid < 256)
      aux[(long)bx * 8192 + bz * 2048 + by * 256 + tid] = pf[tid];
  }
}

// ===========================================================================
// gemm32 MFR=2 (r9, measured fastest projection): 128x128, 2-barrier, 4/CU+.
// ===========================================================================
template<int MFR, int EPI, bool OUT_BF16, bool HAS_BIAS>
__global__ __launch_bounds__(256, (MFR == 2 ? 4 : 6))
void gemm32(const ushort_t* __restrict__ A, const ushort_t* __restrict__ A2,
            int nsplit, const ushort_t* __restrict__ Bt,
            void* __restrict__ Cp, const float* __restrict__ bias,
            float* __restrict__ aux,
            int gx, int gy, int K, int lda, int ldb, int ldc,
            long sA, long sB, long sC, float alpha)
{
  constexpr int ATILE = 2048 * MFR;
  constexpr int BUFSZ = ATILE + 4096;
  __shared__ __align__(16) ushort_t sm[2 * BUFSZ];
  const int tid = threadIdx.x;
  const int lane = tid & 63;
  const int w = tid >> 6;
  const int wr = w >> 1, wc = w & 1;

  const int per = gridDim.x >> 3;
  int wg = blockIdx.x;
  wg = (wg & 7) * per + (wg >> 3);
  const int bz = wg / (gx * gy);
  const int rr = wg - bz * gx * gy;
  const int by = rr / gx, bx = rr - by * gx;
  const int bm = by * (64 * MFR), bn = bx * 128;

  const ushort_t* Ab = (bn >= nsplit) ? A2 : A;

  const int rA0 = (w * MFR) * 16 + (lane >> 2);
  const int cswA = (((lane & 3) ^ ((rA0 >> 1) & 3)) << 3);
  const int rB0 = (w * 2) * 16 + (lane >> 2);
  const int cswB = (((lane & 3) ^ ((rB0 >> 1) & 3)) << 3);
  const ushort_t* pA0 = Ab + (long)bz * sA + (long)(bm + rA0) * lda + cswA;
  const ushort_t* pB0 = Bt + (long)bz * sB + (long)(bn + rB0) * ldb + cswB;

  auto stage = [&](int kt, int buf) {
    const int k0 = kt << 5;
    ushort_t* s = sm + buf * BUFSZ;
#pragma unroll
    for (int i = 0; i < MFR; ++i)
      gload16(pA0 + i * 16 * lda + k0, s + (w * MFR + i) * 512);
#pragma unroll
    for (int i = 0; i < 2; ++i)
      gload16(pB0 + i * 16 * ldb + k0, s + ATILE + (w * 2 + i) * 512);
  };

  const int l31 = lane & 31, kh = lane >> 5;
  int offA[MFR][2], offB[2][2];
#pragma unroll
  for (int m = 0; m < MFR; ++m) {
    const int row = wr * (32 * MFR) + m * 32 + l31;
#pragma unroll
    for (int s = 0; s < 2; ++s)
      offA[m][s] = row * 32 + (((s * 2 + kh) ^ ((row >> 1) & 3)) << 3);
  }
#pragma unroll
  for (int n = 0; n < 2; ++n) {
    const int row = wc * 64 + n * 32 + l31;
#pragma unroll
    for (int s = 0; s < 2; ++s)
      offB[n][s] = ATILE + row * 32 + (((s * 2 + kh) ^ ((row >> 1) & 3)) << 3);
  }

  f32x16_t acc[MFR][2];
#pragma unroll
  for (int m = 0; m < MFR; ++m)
#pragma unroll
    for (int n = 0; n < 2; ++n)
#pragma unroll
      for (int i = 0; i < 16; ++i) acc[m][n][i] = 0.f;

  stage(0, 0);
  __syncthreads();

#define LDX(off) __builtin_bit_cast(bf16x8_t, *(const uint4*)(sp + (off)))
  const int nt = K >> 5;
  for (int kt = 0; kt < nt; ++kt) {
    const int cur = kt & 1;
    if (kt + 1 < nt) stage(kt + 1, cur ^ 1);
    const ushort_t* sp = sm + cur * BUFSZ;
    bf16x8_t af[MFR][2], bfv[2][2];
#pragma unroll
    for (int m = 0; m < MFR; ++m)
#pragma unroll
      for (int s = 0; s < 2; ++s) af[m][s] = LDX(offA[m][s]);
#pragma unroll
    for (int n = 0; n < 2; ++n)
#pragma unroll
      for (int s = 0; s < 2; ++s) bfv[n][s] = LDX(offB[n][s]);
    __builtin_amdgcn_s_setprio(1);
#pragma unroll
    for (int s = 0; s < 2; ++s)
#pragma unroll
      for (int m = 0; m < MFR; ++m)
#pragma unroll
        for (int n = 0; n < 2; ++n)
          acc[m][n] = __builtin_amdgcn_mfma_f32_32x32x16_bf16(
              af[m][s], bfv[n][s], acc[m][n], 0, 0, 0);
    __builtin_amdgcn_s_setprio(0);
    __syncthreads();
  }
#undef LDX

  const long zC = (long)bz * sC;
#pragma unroll
  for (int m = 0; m < MFR; ++m) {
    const int growb = bm + wr * (32 * MFR) + m * 32;
#pragma unroll
    for (int n = 0; n < 2; ++n) {
      const int gcol = bn + wc * 64 + n * 32 + l31;
      float bv_ = 0.f;
      if constexpr (HAS_BIAS) bv_ = bias[gcol];
#pragma unroll
      for (int r = 0; r < 16; ++r) {
        const int grow = growb + (r & 3) + 8 * (r >> 2) + 4 * kh;
        const float v = acc[m][n][r] * alpha + bv_;
        if constexpr (OUT_BF16) {
          ((ushort_t*)Cp)[zC + (long)grow * ldc + gcol] = f2bf(v);
        } else {
          ((float*)Cp)[zC + (long)grow * ldc + gcol] = v;
        }
      }
    }
  }
}

// inv[r] = 1 / sum_k psumG[k][r],  8 col-chunks, 8192 rows
__global__ __launch_bounds__(256)
void invrow(const float* __restrict__ psumG, float* __restrict__ inv) {
  const int r = blockIdx.x * 256 + threadIdx.x;
  float s = 0.f;
#pragma unroll
  for (int k = 0; k < 8; ++k) s += psumG[(long)k * 8192 + r];
  inv[r] = 1.0f / s;
}

// fp32 -> bf16 bulk convert for x and y in one launch (8 elems/thread)
__global__ __launch_bounds__(256)
void conv2(const float* __restrict__ x, const float* __restrict__ y,
           ushort_t* __restrict__ xb, ushort_t* __restrict__ yb) {
  const int b = blockIdx.x;
  const float* in = (b < 4096) ? x : y;
  ushort_t* out = (b < 4096) ? xb : yb;
  const long i = (long)(b & 4095) * 256 + threadIdx.x;
  const float4 a = ((const float4*)in)[i * 2];
  const float4 c = ((const float4*)in)[i * 2 + 1];
  uint4 o;
  o.x = (unsigned)f2bf(a.x) | ((unsigned)f2bf(a.y) << 16);
  o.y = (unsigned)f2bf(a.z) | ((unsigned)f2bf(a.w) << 16);
  o.z = (unsigned)f2bf(c.x) | ((unsigned)f2bf(c.y) << 16);
  o.w = (unsigned)f2bf(c.z) | ((unsigned)f2bf(c.w) << 16);
  ((uint4*)out)[i] = o;
}

// Wt[n][k] = (bf16) W[k][n], D=1024, 3 weights -> contiguous [3072][1024]
__global__ __launch_bounds__(256)
void wtrans3(const float* __restrict__ W0, const float* __restrict__ W1,
             const float* __restrict__ W2, ushort_t* __restrict__ T0,
             ushort_t* __restrict__ T1, ushort_t* __restrict__ T2) {
  const float* W = (blockIdx.z == 0) ? W0 : (blockIdx.z == 1) ? W1 : W2;
  ushort_t* Wt = (blockIdx.z == 0) ? T0 : (blockIdx.z == 1) ? T1 : T2;
  __shared__ float tile[32][33];
  const int bx = blockIdx.x * 32;
  const int by = blockIdx.y * 32;
  const int t = threadIdx.x;
  const int c = t & 31, r0 = t >> 5;
#pragma unroll
  for (int i = 0; i < 4; ++i)
    tile[r0 + i * 8][c] = W[(long)(by + r0 + i * 8) * 1024 + bx + c];
  __syncthreads();
#pragma unroll
  for (int i = 0; i < 4; ++i)
    Wt[(long)(bx + r0 + i * 8) * 1024 + by + c] = f2bf(tile[c][r0 + i * 8]);
}

// bias3 = bq || bk || bv  [3072]
__global__ __launch_bounds__(256)
void bconcat3(const float* __restrict__ a, const float* __restrict__ b,
              const float* __restrict__ c, float* __restrict__ o) {
  const int i = blockIdx.x * 256 + threadIdx.x;
  o[i] = (i < 1024) ? a[i] : (i < 2048) ? b[i - 1024] : c[i - 2048];
}

// bf16 transpose with strides: out[c][r] = in[r][c], 64x64 tiles per batch
__global__ __launch_bounds__(256)
void transpose_bf16(const ushort_t* __restrict__ in, ushort_t* __restrict__ out,
                    int ld_in, int ld_out, long in_bs, long out_bs) {
  __shared__ ushort_t tt[64][65];
  in += (long)blockIdx.z * in_bs;
  out += (long)blockIdx.z * out_bs;
  const int r0 = blockIdx.y * 64, c0 = blockIdx.x * 64;
  const int tc = threadIdx.x & 31;
  const int tr = threadIdx.x >> 5;
#pragma unroll
  for (int i = 0; i < 8; ++i) {
    const unsigned v = *(const unsigned*)(in + (long)(r0 + tr + 8 * i) * ld_in + c0 + tc * 2);
    tt[tr + 8 * i][tc * 2] = (ushort_t)(v & 0xffff);
    tt[tr + 8 * i][tc * 2 + 1] = (ushort_t)(v >> 16);
  }
  __syncthreads();
#pragma unroll
  for (int i = 0; i < 8; ++i) {
    const unsigned v = (unsigned)tt[tc * 2][tr + 8 * i] |
                       ((unsigned)tt[tc * 2 + 1][tr + 8 * i] << 16);
    *(unsigned*)(out + (long)(c0 + tr + 8 * i) * ld_out + r0 + tc * 2) = v;
  }
}

extern "C" void kernel_launch(void* const* d_in, const int* in_sizes, int n_in,
                              void* d_out, int out_size, void* d_ws, size_t ws_size,
                              hipStream_t stream) {
  const float* x  = (const float*)d_in[0];
  const float* y  = (const float*)d_in[1];
  const float* Wq = (const float*)d_in[2];
  const float* bq = (const float*)d_in[3];
  const float* Wk = (const float*)d_in[4];
  const float* bk = (const float*)d_in[5];
  const float* Wv = (const float*)d_in[6];
  const float* bv = (const float*)d_in[7];
  float* out = (float*)d_out;

  const int D = 1024;
  const long MB_ = 1l << 20;

  ushort_t* ws   = (ushort_t*)d_ws;
  ushort_t* Wall = ws;                   // [3072][1024] bf16
  ushort_t* QKV8 = ws + 3 * MB_;         // [8192][3072] bf16
  ushort_t* Sb   = ws + 27 * MB_;        // [B][2048][2048] bf16 (aliases yb/xb)
  ushort_t* yb   = ws + 27 * MB_;
  ushort_t* xb   = ws + 35 * MB_;
  ushort_t* Vt   = ws + 43 * MB_;        // [B][1024][2048] bf16
  float*    bias3 = (float*)(ws + 51 * MB_);
  float*    psumG = (float*)(ws + 51 * MB_ + 8192);  // [8][8192] f32
  float*    inv   = psumG + 8 * 8192;                // [8192] f32

  dim3 blk(256);

  conv2<<<dim3(8192), blk, 0, stream>>>(x, y, xb, yb);
  wtrans3<<<dim3(32, 32, 3), blk, 0, stream>>>(
      Wq, Wk, Wv, Wall, Wall + 1 * MB_, Wall + 2 * MB_);
  bconcat3<<<dim3(12), blk, 0, stream>>>(bq, bk, bv, bias3);

  // QKV8 = [xb|yb] @ Wall^T + bias3 -> [8192][3072]; grid 24x64 = 1536
  gemm32<2, 0, true, true><<<dim3(1536), blk, 0, stream>>>(
      xb, yb, 1024, Wall, QKV8, bias3, nullptr,
      24, 64, D, D, D, 3072, 0, 0, 0, 1.0f);

  // Vt[b][d][t] = QKV8[b*2048+t][2048+d]
  transpose_bf16<<<dim3(16, 32, 4), blk, 0, stream>>>(
      QKV8 + 2048, Vt, 3072, 2048, 2048l * 3072, 1024l * 2048);

  // P' = exp((Q K^T)/32) -> bf16 [B][2048][2048] + row partial sums
  // gemm_big BN=256: grid 8x8x4 = 256 (1/CU), wave tile 128x64
  gemm_big<256, 1><<<dim3(256), dim3(512), 0, stream>>>(
      QKV8, QKV8 + 1024, Sb, psumG,
      8, 8, D, 3072, 3072, 2048,
      2048l * 3072, 2048l * 3072, 2048l * 2048, 0.03125f);

  invrow<<<dim3(32), blk, 0, stream>>>(psumG, inv);

  // out = (P' @ V) * inv[row]; gemm_big BN=128: grid 8x8x4 = 256 (2/CU)
  gemm_big<128, 2><<<dim3(256), dim3(256), 0, stream>>>(
      Sb, Vt, out, inv,
      8, 8, 2048, 2048, 2048, D,
      2048l * 2048, 1024l * 2048, 2048l * 1024, 1.0f);
}

// Round 11
// 202.845 us; speedup vs baseline: 1.1659x; 1.0174x over previous
//
#include <hip/hip_runtime.h>

typedef __bf16 bf16x8_t __attribute__((ext_vector_type(8)));
typedef float f32x16_t __attribute__((ext_vector_type(16)));
typedef unsigned short ushort_t;

__device__ __forceinline__ unsigned short f2bf(float f) {
  unsigned u = __float_as_uint(f);
  u = (u + 0x7FFFu + ((u >> 16) & 1u)) >> 16;
  return (unsigned short)u;
}
__device__ __forceinline__ float bf2f(unsigned short h) {
  return __uint_as_float(((unsigned)h) << 16);
}

// async global->LDS, 16B/lane. LDS dest = wave-uniform base + lane*16.
__device__ __forceinline__ void gload16(const void* g, void* l) {
  __builtin_amdgcn_global_load_lds(
      (const __attribute__((address_space(1))) unsigned int*)g,
      (__attribute__((address_space(3))) unsigned int*)l, 16, 0, 0);
}

// ===========================================================================
// gemm_qkv: QKV projection with fp32 A read in-kernel (conv2 deleted).
// Fixed: M=8192, N=3072, K=1024; C[8192][3072] bf16 = [x|y] @ Wall^T + bias3.
// Structure = r7/r9-proven gemm32 MFR=2 (128x128 tile, BK=32, 4 waves 2x2,
// 2-buffer, 1 __syncthreads/K-tile). A-path: T14 split — float4 loads issued
// at iter top (with B's gload_lds), convert+ds_write AFTER the MFMAs into the
// idle buffer (vmcnt wait lands post-MFMA). ds_write dest mirrors gload16's
// base+lane*16B mapping, so fragment reads are unchanged.
// Swizzle g(row)=(row>>1)&3 both sides. C/D 32x32: col=lane&31,
// row=(reg&3)+8*(reg>>2)+4*(lane>>5)  [m74/m101]
// ===========================================================================
__global__ __launch_bounds__(256, 4)
void gemm_qkv(const float* __restrict__ X, const float* __restrict__ Y,
              const ushort_t* __restrict__ Bt, ushort_t* __restrict__ Cp,
              const float* __restrict__ bias)
{
  constexpr int ATILE = 4096;            // ushorts: A[128][32]
  constexpr int BUFSZ = ATILE + 4096;    // + B[128][32]
  __shared__ __align__(16) ushort_t sm[2 * BUFSZ];
  const int tid = threadIdx.x;
  const int lane = tid & 63;
  const int w = tid >> 6;
  const int wr = w >> 1, wc = w & 1;

  // bijective XCD-chunked swizzle (1536 % 8 == 0)
  const int per = gridDim.x >> 3;
  int wg = blockIdx.x;
  wg = (wg & 7) * per + (wg >> 3);
  const int by = wg / 24, bx = wg - by * 24;   // 64 row-bands x 24 col-tiles
  const int bm = by * 128, bn = bx * 128;

  const float* Af = (bn >= 1024) ? Y : X;      // Q cols read x, K/V read y

  // A staging: slot=w*2+i covers rows slot*16+(lane>>2), chunk lane&3 (swz)
  const int rA0 = (w * 2) * 16 + (lane >> 2);
  const int cA = ((lane & 3) ^ ((rA0 >> 1) & 3)) << 3;  // elems (fp32 too)
  const float* pA0 = Af + (long)(bm + rA0) * 1024 + cA;
  const float* pA1 = pA0 + 16 * 1024;
  // B staging via gload_lds
  const ushort_t* pB0 = Bt + (long)(bn + rA0) * 1024 + cA;
  const ushort_t* pB1 = pB0 + 16 * 1024;

  auto stageB = [&](int kt, int buf) {
    const int k0 = kt << 5;
    ushort_t* s = sm + buf * BUFSZ;
    gload16(pB0 + k0, s + ATILE + (w * 2) * 512);
    gload16(pB1 + k0, s + ATILE + (w * 2 + 1) * 512);
  };

  float4 ra[2][2];                              // [slot][half]
  auto loadA = [&](int kt) {
    const int k0 = kt << 5;
    ra[0][0] = *(const float4*)(pA0 + k0);
    ra[0][1] = *(const float4*)(pA0 + k0 + 4);
    ra[1][0] = *(const float4*)(pA1 + k0);
    ra[1][1] = *(const float4*)(pA1 + k0 + 4);
  };
  auto writeA = [&](int buf) {
    ushort_t* s = sm + buf * BUFSZ;
#pragma unroll
    for (int i = 0; i < 2; ++i) {
      uint4 o;
      o.x = (unsigned)f2bf(ra[i][0].x) | ((unsigned)f2bf(ra[i][0].y) << 16);
      o.y = (unsigned)f2bf(ra[i][0].z) | ((unsigned)f2bf(ra[i][0].w) << 16);
      o.z = (unsigned)f2bf(ra[i][1].x) | ((unsigned)f2bf(ra[i][1].y) << 16);
      o.w = (unsigned)f2bf(ra[i][1].z) | ((unsigned)f2bf(ra[i][1].w) << 16);
      *(uint4*)(s + (w * 2 + i) * 512 + lane * 8) = o;  // = gload16 dest map
    }
  };

  // fragment ds_read offsets
  const int l31 = lane & 31, kh = lane >> 5;
  int offA[2][2], offB[2][2];
#pragma unroll
  for (int m = 0; m < 2; ++m) {
    const int row = wr * 64 + m * 32 + l31;
#pragma unroll
    for (int s = 0; s < 2; ++s)
      offA[m][s] = row * 32 + (((s * 2 + kh) ^ ((row >> 1) & 3)) << 3);
  }
#pragma unroll
  for (int n = 0; n < 2; ++n) {
    const int row = wc * 64 + n * 32 + l31;
#pragma unroll
    for (int s = 0; s < 2; ++s)
      offB[n][s] = ATILE + row * 32 + (((s * 2 + kh) ^ ((row >> 1) & 3)) << 3);
  }

  f32x16_t acc[2][2];
#pragma unroll
  for (int m = 0; m < 2; ++m)
#pragma unroll
    for (int n = 0; n < 2; ++n)
#pragma unroll
      for (int i = 0; i < 16; ++i) acc[m][n][i] = 0.f;

  // prologue
  loadA(0);
  stageB(0, 0);
  writeA(0);
  __syncthreads();

#define LDX(off) __builtin_bit_cast(bf16x8_t, *(const uint4*)(sp + (off)))
  const int nt = 1024 >> 5;  // 32
  for (int kt = 0; kt < nt; ++kt) {
    const int cur = kt & 1;
    const bool more = (kt + 1 < nt);
    if (more) { stageB(kt + 1, cur ^ 1); loadA(kt + 1); }
    const ushort_t* sp = sm + cur * BUFSZ;
    bf16x8_t af[2][2], bfv[2][2];
#pragma unroll
    for (int m = 0; m < 2; ++m)
#pragma unroll
      for (int s = 0; s < 2; ++s) af[m][s] = LDX(offA[m][s]);
#pragma unroll
    for (int n = 0; n < 2; ++n)
#pragma unroll
      for (int s = 0; s < 2; ++s) bfv[n][s] = LDX(offB[n][s]);
    __builtin_amdgcn_s_setprio(1);
#pragma unroll
    for (int s = 0; s < 2; ++s)
#pragma unroll
      for (int m = 0; m < 2; ++m)
#pragma unroll
        for (int n = 0; n < 2; ++n)
          acc[m][n] = __builtin_amdgcn_mfma_f32_32x32x16_bf16(
              af[m][s], bfv[n][s], acc[m][n], 0, 0, 0);
    __builtin_amdgcn_s_setprio(0);
    if (more) writeA(cur ^ 1);     // vmcnt wait lands here, after the MFMAs
    __syncthreads();
  }
#undef LDX

  // epilogue: bias + bf16 store
#pragma unroll
  for (int m = 0; m < 2; ++m) {
    const int growb = bm + wr * 64 + m * 32;
#pragma unroll
    for (int n = 0; n < 2; ++n) {
      const int gcol = bn + wc * 64 + n * 32 + l31;
      const float bv_ = bias[gcol];
#pragma unroll
      for (int r = 0; r < 16; ++r) {
        const int grow = growb + (r & 3) + 8 * (r >> 2) + 4 * kh;
        Cp[(long)grow * 3072 + gcol] = f2bf(acc[m][n][r] + bv_);
      }
    }
  }
}

// ===========================================================================
// gemm_big (r10, unchanged): 256xBN NT GEMM, wave tile 128x64, 2-barrier loop.
// EPI: 1 exp(alpha*acc)+row-partial-sums->aux | 2 scale by aux[row].
// ===========================================================================
template<int BN, int EPI>
__global__ __launch_bounds__((BN / 64) * 128, 2)
void gemm_big(const ushort_t* __restrict__ A, const ushort_t* __restrict__ Bt,
              void* __restrict__ Cp, float* __restrict__ aux,
              int gx, int gy, int K, int lda, int ldb, int ldc,
              long sA, long sB, long sC, float alpha)
{
  constexpr int WC = BN / 64;
  constexpr int NW = 2 * WC;
  constexpr int BUFSZ = 8192 + BN * 32;
  constexpr int A_SPW = 16 / NW;
  constexpr int B_SPW = (BN / 16) / NW;
  __shared__ __align__(16) ushort_t sm[2 * BUFSZ];

  const int tid = threadIdx.x;
  const int lane = tid & 63;
  const int w = tid >> 6;
  const int wr = w / WC, wc = w % WC;

  const int per = gridDim.x >> 3;
  int wg = blockIdx.x;
  wg = (wg & 7) * per + (wg >> 3);
  const int bz = wg / (gx * gy);
  const int rr = wg - bz * gx * gy;
  const int by = rr / gx, bx = rr - by * gx;
  const int bm = by * 256, bn = bx * BN;

  const int csw = (((lane & 3) ^ ((lane >> 3) & 3)) << 3);
  const ushort_t* pA = A + (long)bz * sA +
      (long)(bm + w * (A_SPW * 16) + (lane >> 2)) * lda + csw;
  const ushort_t* pB = Bt + (long)bz * sB +
      (long)(bn + w * (B_SPW * 16) + (lane >> 2)) * ldb + csw;

  auto stage = [&](int kt, int buf) {
    const int k0 = kt << 5;
    ushort_t* s = sm + buf * BUFSZ;
#pragma unroll
    for (int i = 0; i < A_SPW; ++i)
      gload16(pA + (long)(i * 16) * lda + k0, s + (w * A_SPW + i) * 512);
#pragma unroll
    for (int i = 0; i < B_SPW; ++i)
      gload16(pB + (long)(i * 16) * ldb + k0, s + 8192 + (w * B_SPW + i) * 512);
  };

  const int l31 = lane & 31, kh = lane >> 5;
  const int sw3 = (lane >> 1) & 3;
  int offA[4][2], offB[2][2];
#pragma unroll
  for (int mf = 0; mf < 4; ++mf)
#pragma unroll
    for (int ks = 0; ks < 2; ++ks)
      offA[mf][ks] = (wr * 128 + mf * 32 + l31) * 32 +
                     (((ks * 2 + kh) ^ sw3) << 3);
#pragma unroll
  for (int nf = 0; nf < 2; ++nf)
#pragma unroll
    for (int ks = 0; ks < 2; ++ks)
      offB[nf][ks] = 8192 + (wc * 64 + nf * 32 + l31) * 32 +
                     (((ks * 2 + kh) ^ sw3) << 3);

  f32x16_t acc[4][2];
#pragma unroll
  for (int m = 0; m < 4; ++m)
#pragma unroll
    for (int n = 0; n < 2; ++n)
#pragma unroll
      for (int i = 0; i < 16; ++i) acc[m][n][i] = 0.f;

  stage(0, 0);
  __syncthreads();

#define LDX(off) __builtin_bit_cast(bf16x8_t, *(const uint4*)(sp + (off)))
  const int nt = K >> 5;
  for (int kt = 0; kt < nt; ++kt) {
    const int cur = kt & 1;
    if (kt + 1 < nt) stage(kt + 1, cur ^ 1);
    const ushort_t* sp = sm + cur * BUFSZ;
    bf16x8_t af[4][2], bfv[2][2];
#pragma unroll
    for (int mf = 0; mf < 4; ++mf)
#pragma unroll
      for (int ks = 0; ks < 2; ++ks) af[mf][ks] = LDX(offA[mf][ks]);
#pragma unroll
    for (int nf = 0; nf < 2; ++nf)
#pragma unroll
      for (int ks = 0; ks < 2; ++ks) bfv[nf][ks] = LDX(offB[nf][ks]);
    __builtin_amdgcn_s_setprio(1);
#pragma unroll
    for (int ks = 0; ks < 2; ++ks)
#pragma unroll
      for (int mf = 0; mf < 4; ++mf)
#pragma unroll
        for (int nf = 0; nf < 2; ++nf)
          acc[mf][nf] = __builtin_amdgcn_mfma_f32_32x32x16_bf16(
              af[mf][ks], bfv[nf][ks], acc[mf][nf], 0, 0, 0);
    __builtin_amdgcn_s_setprio(0);
    __syncthreads();
  }
#undef LDX

  const long zC = (long)bz * sC;
  float* pf = (float*)sm;
  if constexpr (EPI == 1) {
    if (tid < 256) pf[tid] = 0.f;
    __syncthreads();
  }
#pragma unroll
  for (int mf = 0; mf < 4; ++mf) {
    const int growb = bm + wr * 128 + mf * 32;
    float part[16];
    if constexpr (EPI == 1) {
#pragma unroll
      for (int r = 0; r < 16; ++r) part[r] = 0.f;
    }
#pragma unroll
    for (int nf = 0; nf < 2; ++nf) {
      const int gcol = bn + wc * 64 + nf * 32 + l31;
#pragma unroll
      for (int r = 0; r < 16; ++r) {
        const int grow = growb + (r & 3) + 8 * (r >> 2) + 4 * kh;
        float v = acc[mf][nf][r] * alpha;
        if constexpr (EPI == 1) {
          const ushort_t pb = f2bf(__expf(v));
          ((ushort_t*)Cp)[zC + (long)grow * ldc + gcol] = pb;
          part[r] += bf2f(pb);
        } else if constexpr (EPI == 2) {
          v *= aux[bz * 2048 + grow];
          ((float*)Cp)[zC + (long)grow * ldc + gcol] = v;
        } else {
          ((ushort_t*)Cp)[zC + (long)grow * ldc + gcol] = f2bf(v);
        }
      }
    }
    if constexpr (EPI == 1) {
#pragma unroll
      for (int step = 1; step < 32; step <<= 1)
#pragma unroll
        for (int r = 0; r < 16; ++r) part[r] += __shfl_xor(part[r], step, 64);
      if (l31 == 0) {
#pragma unroll
        for (int r = 0; r < 16; ++r) {
          const int rloc = wr * 128 + mf * 32 + (r & 3) + 8 * (r >> 2) + 4 * kh;
          atomicAdd(&pf[rloc], part[r]);
        }
      }
    }
  }
  if constexpr (EPI == 1) {
    __syncthreads();
    if (tid < 256)
      aux[(long)bx * 8192 + bz * 2048 + by * 256 + tid] = pf[tid];
  }
}

// inv[r] = 1 / sum_k psumG[k][r],  8 col-chunks, 8192 rows
__global__ __launch_bounds__(256)
void invrow(const float* __restrict__ psumG, float* __restrict__ inv) {
  const int r = blockIdx.x * 256 + threadIdx.x;
  float s = 0.f;
#pragma unroll
  for (int k = 0; k < 8; ++k) s += psumG[(long)k * 8192 + r];
  inv[r] = 1.0f / s;
}

// Wt[n][k] = (bf16) W[k][n], D=1024, 3 weights -> contiguous [3072][1024]
__global__ __launch_bounds__(256)
void wtrans3(const float* __restrict__ W0, const float* __restrict__ W1,
             const float* __restrict__ W2, ushort_t* __restrict__ T0,
             ushort_t* __restrict__ T1, ushort_t* __restrict__ T2) {
  const float* W = (blockIdx.z == 0) ? W0 : (blockIdx.z == 1) ? W1 : W2;
  ushort_t* Wt = (blockIdx.z == 0) ? T0 : (blockIdx.z == 1) ? T1 : T2;
  __shared__ float tile[32][33];
  const int bx = blockIdx.x * 32;
  const int by = blockIdx.y * 32;
  const int t = threadIdx.x;
  const int c = t & 31, r0 = t >> 5;
#pragma unroll
  for (int i = 0; i < 4; ++i)
    tile[r0 + i * 8][c] = W[(long)(by + r0 + i * 8) * 1024 + bx + c];
  __syncthreads();
#pragma unroll
  for (int i = 0; i < 4; ++i)
    Wt[(long)(bx + r0 + i * 8) * 1024 + by + c] = f2bf(tile[c][r0 + i * 8]);
}

// bias3 = bq || bk || bv  [3072]
__global__ __launch_bounds__(256)
void bconcat3(const float* __restrict__ a, const float* __restrict__ b,
              const float* __restrict__ c, float* __restrict__ o) {
  const int i = blockIdx.x * 256 + threadIdx.x;
  o[i] = (i < 1024) ? a[i] : (i < 2048) ? b[i - 1024] : c[i - 2048];
}

// bf16 transpose with strides: out[c][r] = in[r][c], 64x64 tiles per batch
__global__ __launch_bounds__(256)
void transpose_bf16(const ushort_t* __restrict__ in, ushort_t* __restrict__ out,
                    int ld_in, int ld_out, long in_bs, long out_bs) {
  __shared__ ushort_t tt[64][65];
  in += (long)blockIdx.z * in_bs;
  out += (long)blockIdx.z * out_bs;
  const int r0 = blockIdx.y * 64, c0 = blockIdx.x * 64;
  const int tc = threadIdx.x & 31;
  const int tr = threadIdx.x >> 5;
#pragma unroll
  for (int i = 0; i < 8; ++i) {
    const unsigned v = *(const unsigned*)(in + (long)(r0 + tr + 8 * i) * ld_in + c0 + tc * 2);
    tt[tr + 8 * i][tc * 2] = (ushort_t)(v & 0xffff);
    tt[tr + 8 * i][tc * 2 + 1] = (ushort_t)(v >> 16);
  }
  __syncthreads();
#pragma unroll
  for (int i = 0; i < 8; ++i) {
    const unsigned v = (unsigned)tt[tc * 2][tr + 8 * i] |
                       ((unsigned)tt[tc * 2 + 1][tr + 8 * i] << 16);
    *(unsigned*)(out + (long)(c0 + tr + 8 * i) * ld_out + r0 + tc * 2) = v;
  }
}

extern "C" void kernel_launch(void* const* d_in, const int* in_sizes, int n_in,
                              void* d_out, int out_size, void* d_ws, size_t ws_size,
                              hipStream_t stream) {
  const float* x  = (const float*)d_in[0];
  const float* y  = (const float*)d_in[1];
  const float* Wq = (const float*)d_in[2];
  const float* bq = (const float*)d_in[3];
  const float* Wk = (const float*)d_in[4];
  const float* bk = (const float*)d_in[5];
  const float* Wv = (const float*)d_in[6];
  const float* bv = (const float*)d_in[7];
  float* out = (float*)d_out;

  const int D = 1024;
  const long MB_ = 1l << 20;

  ushort_t* ws   = (ushort_t*)d_ws;
  ushort_t* Wall = ws;                   // [3072][1024] bf16
  ushort_t* QKV8 = ws + 3 * MB_;         // [8192][3072] bf16
  ushort_t* Sb   = ws + 27 * MB_;        // [B][2048][2048] bf16
  ushort_t* Vt   = ws + 43 * MB_;        // [B][1024][2048] bf16
  float*    bias3 = (float*)(ws + 51 * MB_);
  float*    psumG = (float*)(ws + 51 * MB_ + 8192);  // [8][8192] f32
  float*    inv   = psumG + 8 * 8192;                // [8192] f32

  dim3 blk(256);

  wtrans3<<<dim3(32, 32, 3), blk, 0, stream>>>(
      Wq, Wk, Wv, Wall, Wall + 1 * MB_, Wall + 2 * MB_);
  bconcat3<<<dim3(12), blk, 0, stream>>>(bq, bk, bv, bias3);

  // QKV8 = [x|y] @ Wall^T + bias3 -> [8192][3072]; fp32 A in-kernel
  gemm_qkv<<<dim3(1536), blk, 0, stream>>>(x, y, Wall, QKV8, bias3);

  // Vt[b][d][t] = QKV8[b*2048+t][2048+d]
  transpose_bf16<<<dim3(16, 32, 4), blk, 0, stream>>>(
      QKV8 + 2048, Vt, 3072, 2048, 2048l * 3072, 1024l * 2048);

  // P' = exp((Q K^T)/32) -> bf16 [B][2048][2048] + row partial sums
  gemm_big<256, 1><<<dim3(256), dim3(512), 0, stream>>>(
      QKV8, QKV8 + 1024, Sb, psumG,
      8, 8, D, 3072, 3072, 2048,
      2048l * 3072, 2048l * 3072, 2048l * 2048, 0.03125f);

  invrow<<<dim3(32), blk, 0, stream>>>(psumG, inv);

  // out = (P' @ V) * inv[row]
  gemm_big<128, 2><<<dim3(256), blk, 0, stream>>>(
      Sb, Vt, out, inv,
      8, 8, 2048, 2048, 2048, D,
      2048l * 2048, 1024l * 2048, 2048l * 1024, 1.0f);
}

// Round 12
// 192.324 us; speedup vs baseline: 1.2297x; 1.0547x over previous
//
#include <hip/hip_runtime.h>

typedef __bf16 bf16x8_t __attribute__((ext_vector_type(8)));
typedef float f32x16_t __attribute__((ext_vector_type(16)));
typedef unsigned short ushort_t;

__device__ __forceinline__ unsigned short f2bf(float f) {
  unsigned u = __float_as_uint(f);
  u = (u + 0x7FFFu + ((u >> 16) & 1u)) >> 16;
  return (unsigned short)u;
}
__device__ __forceinline__ float bf2f(unsigned short h) {
  return __uint_as_float(((unsigned)h) << 16);
}

// async global->LDS, 16B/lane. LDS dest = wave-uniform base + lane*16.
__device__ __forceinline__ void gload16(const void* g, void* l) {
  __builtin_amdgcn_global_load_lds(
      (const __attribute__((address_space(1))) unsigned int*)g,
      (__attribute__((address_space(3))) unsigned int*)l, 16, 0, 0);
}

// ===========================================================================
// gemm_qkv2: r10's measured-fastest projection structure (128x128 tile, BK=32,
// 4 waves 2x2 of 64x64, gload_lds staging, 2-buffer, 1 __syncthreads/K-tile,
// 32KB LDS, 4+ blocks/CU). Fixed dims: M=8192, N=3072, K=1024.
// A-select: Q tiles (bn<1024) read xb, K/V tiles read yb.
// Epilogue: Q/K cols -> QKV8[row][col] (ldc 3072, +bias); V cols (>=2048)
// -> Vt[b][d][t] directly (8B packed stores, 4 contiguous t per acc quad),
// deleting the separate transpose kernel.
// Swizzle g(row)=(row>>1)&3 both sides. C/D 32x32: col=lane&31,
// row=(reg&3)+8*(reg>>2)+4*(lane>>5)  [m74/m101]
// ===========================================================================
__global__ __launch_bounds__(256, 4)
void gemm_qkv2(const ushort_t* __restrict__ Xb, const ushort_t* __restrict__ Yb,
               const ushort_t* __restrict__ Bt, ushort_t* __restrict__ Cp,
               ushort_t* __restrict__ Vt, const float* __restrict__ bias)
{
  constexpr int ATILE = 4096;            // ushorts: A[128][32]
  constexpr int BUFSZ = 8192;            // + B[128][32]
  __shared__ __align__(16) ushort_t sm[2 * BUFSZ];
  const int tid = threadIdx.x;
  const int lane = tid & 63;
  const int w = tid >> 6;
  const int wr = w >> 1, wc = w & 1;

  // bijective XCD-chunked swizzle (1536 % 8 == 0)
  const int per = gridDim.x >> 3;
  int wg = blockIdx.x;
  wg = (wg & 7) * per + (wg >> 3);
  const int by = wg / 24, bx = wg - by * 24;   // 64 row-bands x 24 col-tiles
  const int bm = by * 128, bn = bx * 128;

  const ushort_t* Ab = (bn >= 1024) ? Yb : Xb;

  // staging: slot q=w*2+i covers rows q*16+(lane>>2), chunk lane&3 (src-swz)
  const int r0 = (w * 2) * 16 + (lane >> 2);
  const int csw = (((lane & 3) ^ ((r0 >> 1) & 3)) << 3);
  const ushort_t* pA0 = Ab + (long)(bm + r0) * 1024 + csw;
  const ushort_t* pA1 = pA0 + 16 * 1024;
  const ushort_t* pB0 = Bt + (long)(bn + r0) * 1024 + csw;
  const ushort_t* pB1 = pB0 + 16 * 1024;

  auto stage = [&](int kt, int buf) {
    const int k0 = kt << 5;
    ushort_t* s = sm + buf * BUFSZ;
    gload16(pA0 + k0, s + (w * 2) * 512);
    gload16(pA1 + k0, s + (w * 2 + 1) * 512);
    gload16(pB0 + k0, s + ATILE + (w * 2) * 512);
    gload16(pB1 + k0, s + ATILE + (w * 2 + 1) * 512);
  };

  // fragment ds_read offsets
  const int l31 = lane & 31, kh = lane >> 5;
  int offA[2][2], offB[2][2];
#pragma unroll
  for (int m = 0; m < 2; ++m) {
    const int row = wr * 64 + m * 32 + l31;
#pragma unroll
    for (int s = 0; s < 2; ++s)
      offA[m][s] = row * 32 + (((s * 2 + kh) ^ ((row >> 1) & 3)) << 3);
  }
#pragma unroll
  for (int n = 0; n < 2; ++n) {
    const int row = wc * 64 + n * 32 + l31;
#pragma unroll
    for (int s = 0; s < 2; ++s)
      offB[n][s] = ATILE + row * 32 + (((s * 2 + kh) ^ ((row >> 1) & 3)) << 3);
  }

  f32x16_t acc[2][2];
#pragma unroll
  for (int m = 0; m < 2; ++m)
#pragma unroll
    for (int n = 0; n < 2; ++n)
#pragma unroll
      for (int i = 0; i < 16; ++i) acc[m][n][i] = 0.f;

  stage(0, 0);
  __syncthreads();

#define LDX(off) __builtin_bit_cast(bf16x8_t, *(const uint4*)(sp + (off)))
  const int nt = 32;  // K=1024 / 32
  for (int kt = 0; kt < nt; ++kt) {
    const int cur = kt & 1;
    if (kt + 1 < nt) stage(kt + 1, cur ^ 1);   // in flight across MFMAs
    const ushort_t* sp = sm + cur * BUFSZ;
    bf16x8_t af[2][2], bfv[2][2];
#pragma unroll
    for (int m = 0; m < 2; ++m)
#pragma unroll
      for (int s = 0; s < 2; ++s) af[m][s] = LDX(offA[m][s]);
#pragma unroll
    for (int n = 0; n < 2; ++n)
#pragma unroll
      for (int s = 0; s < 2; ++s) bfv[n][s] = LDX(offB[n][s]);
    __builtin_amdgcn_s_setprio(1);
#pragma unroll
    for (int s = 0; s < 2; ++s)
#pragma unroll
      for (int m = 0; m < 2; ++m)
#pragma unroll
        for (int n = 0; n < 2; ++n)
          acc[m][n] = __builtin_amdgcn_mfma_f32_32x32x16_bf16(
              af[m][s], bfv[n][s], acc[m][n], 0, 0, 0);
    __builtin_amdgcn_s_setprio(0);
    __syncthreads();
  }
#undef LDX

  // epilogue
#pragma unroll
  for (int m = 0; m < 2; ++m) {
    const int growb = bm + wr * 64 + m * 32;
#pragma unroll
    for (int n = 0; n < 2; ++n) {
      const int gcol = bn + wc * 64 + n * 32 + l31;
      const float bv_ = bias[gcol];
      if (gcol < 2048) {        // Q/K: normal layout into QKV8
#pragma unroll
        for (int r = 0; r < 16; ++r) {
          const int grow = growb + (r & 3) + 8 * (r >> 2) + 4 * kh;
          Cp[(long)grow * 3072 + gcol] = f2bf(acc[m][n][r] + bv_);
        }
      } else {                  // V: transposed into Vt[b][d][t]
        const int d = gcol - 2048;
#pragma unroll
        for (int rq = 0; rq < 4; ++rq) {
          const int t0 = growb + 8 * rq + 4 * kh;  // 4-aligned, contiguous j
          const int b = t0 >> 11, tt = t0 & 2047;
          unsigned long long w4 =
                (unsigned long long)f2bf(acc[m][n][rq * 4 + 0] + bv_)
              | ((unsigned long long)f2bf(acc[m][n][rq * 4 + 1] + bv_) << 16)
              | ((unsigned long long)f2bf(acc[m][n][rq * 4 + 2] + bv_) << 32)
              | ((unsigned long long)f2bf(acc[m][n][rq * 4 + 3] + bv_) << 48);
          *(unsigned long long*)(Vt + (long)b * (1024l * 2048) +
                                 (long)d * 2048 + tt) = w4;
        }
      }
    }
  }
}

// ===========================================================================
// gemm_big (r10, unchanged): 256xBN NT GEMM, wave tile 128x64, 2-barrier loop.
// EPI: 1 exp(alpha*acc)+row-partial-sums->aux | 2 scale by aux[row].
// ===========================================================================
template<int BN, int EPI>
__global__ __launch_bounds__((BN / 64) * 128, 2)
void gemm_big(const ushort_t* __restrict__ A, const ushort_t* __restrict__ Bt,
              void* __restrict__ Cp, float* __restrict__ aux,
              int gx, int gy, int K, int lda, int ldb, int ldc,
              long sA, long sB, long sC, float alpha)
{
  constexpr int WC = BN / 64;
  constexpr int NW = 2 * WC;
  constexpr int BUFSZ = 8192 + BN * 32;
  constexpr int A_SPW = 16 / NW;
  constexpr int B_SPW = (BN / 16) / NW;
  __shared__ __align__(16) ushort_t sm[2 * BUFSZ];

  const int tid = threadIdx.x;
  const int lane = tid & 63;
  const int w = tid >> 6;
  const int wr = w / WC, wc = w % WC;

  const int per = gridDim.x >> 3;
  int wg = blockIdx.x;
  wg = (wg & 7) * per + (wg >> 3);
  const int bz = wg / (gx * gy);
  const int rr = wg - bz * gx * gy;
  const int by = rr / gx, bx = rr - by * gx;
  const int bm = by * 256, bn = bx * BN;

  const int csw = (((lane & 3) ^ ((lane >> 3) & 3)) << 3);
  const ushort_t* pA = A + (long)bz * sA +
      (long)(bm + w * (A_SPW * 16) + (lane >> 2)) * lda + csw;
  const ushort_t* pB = Bt + (long)bz * sB +
      (long)(bn + w * (B_SPW * 16) + (lane >> 2)) * ldb + csw;

  auto stage = [&](int kt, int buf) {
    const int k0 = kt << 5;
    ushort_t* s = sm + buf * BUFSZ;
#pragma unroll
    for (int i = 0; i < A_SPW; ++i)
      gload16(pA + (long)(i * 16) * lda + k0, s + (w * A_SPW + i) * 512);
#pragma unroll
    for (int i = 0; i < B_SPW; ++i)
      gload16(pB + (long)(i * 16) * ldb + k0, s + 8192 + (w * B_SPW + i) * 512);
  };

  const int l31 = lane & 31, kh = lane >> 5;
  const int sw3 = (lane >> 1) & 3;
  int offA[4][2], offB[2][2];
#pragma unroll
  for (int mf = 0; mf < 4; ++mf)
#pragma unroll
    for (int ks = 0; ks < 2; ++ks)
      offA[mf][ks] = (wr * 128 + mf * 32 + l31) * 32 +
                     (((ks * 2 + kh) ^ sw3) << 3);
#pragma unroll
  for (int nf = 0; nf < 2; ++nf)
#pragma unroll
    for (int ks = 0; ks < 2; ++ks)
      offB[nf][ks] = 8192 + (wc * 64 + nf * 32 + l31) * 32 +
                     (((ks * 2 + kh) ^ sw3) << 3);

  f32x16_t acc[4][2];
#pragma unroll
  for (int m = 0; m < 4; ++m)
#pragma unroll
    for (int n = 0; n < 2; ++n)
#pragma unroll
      for (int i = 0; i < 16; ++i) acc[m][n][i] = 0.f;

  stage(0, 0);
  __syncthreads();

#define LDX(off) __builtin_bit_cast(bf16x8_t, *(const uint4*)(sp + (off)))
  const int nt = K >> 5;
  for (int kt = 0; kt < nt; ++kt) {
    const int cur = kt & 1;
    if (kt + 1 < nt) stage(kt + 1, cur ^ 1);
    const ushort_t* sp = sm + cur * BUFSZ;
    bf16x8_t af[4][2], bfv[2][2];
#pragma unroll
    for (int mf = 0; mf < 4; ++mf)
#pragma unroll
      for (int ks = 0; ks < 2; ++ks) af[mf][ks] = LDX(offA[mf][ks]);
#pragma unroll
    for (int nf = 0; nf < 2; ++nf)
#pragma unroll
      for (int ks = 0; ks < 2; ++ks) bfv[nf][ks] = LDX(offB[nf][ks]);
    __builtin_amdgcn_s_setprio(1);
#pragma unroll
    for (int ks = 0; ks < 2; ++ks)
#pragma unroll
      for (int mf = 0; mf < 4; ++mf)
#pragma unroll
        for (int nf = 0; nf < 2; ++nf)
          acc[mf][nf] = __builtin_amdgcn_mfma_f32_32x32x16_bf16(
              af[mf][ks], bfv[nf][ks], acc[mf][nf], 0, 0, 0);
    __builtin_amdgcn_s_setprio(0);
    __syncthreads();
  }
#undef LDX

  const long zC = (long)bz * sC;
  float* pf = (float*)sm;
  if constexpr (EPI == 1) {
    if (tid < 256) pf[tid] = 0.f;
    __syncthreads();
  }
#pragma unroll
  for (int mf = 0; mf < 4; ++mf) {
    const int growb = bm + wr * 128 + mf * 32;
    float part[16];
    if constexpr (EPI == 1) {
#pragma unroll
      for (int r = 0; r < 16; ++r) part[r] = 0.f;
    }
#pragma unroll
    for (int nf = 0; nf < 2; ++nf) {
      const int gcol = bn + wc * 64 + nf * 32 + l31;
#pragma unroll
      for (int r = 0; r < 16; ++r) {
        const int grow = growb + (r & 3) + 8 * (r >> 2) + 4 * kh;
        float v = acc[mf][nf][r] * alpha;
        if constexpr (EPI == 1) {
          const ushort_t pb = f2bf(__expf(v));
          ((ushort_t*)Cp)[zC + (long)grow * ldc + gcol] = pb;
          part[r] += bf2f(pb);
        } else if constexpr (EPI == 2) {
          v *= aux[bz * 2048 + grow];
          ((float*)Cp)[zC + (long)grow * ldc + gcol] = v;
        } else {
          ((ushort_t*)Cp)[zC + (long)grow * ldc + gcol] = f2bf(v);
        }
      }
    }
    if constexpr (EPI == 1) {
#pragma unroll
      for (int step = 1; step < 32; step <<= 1)
#pragma unroll
        for (int r = 0; r < 16; ++r) part[r] += __shfl_xor(part[r], step, 64);
      if (l31 == 0) {
#pragma unroll
        for (int r = 0; r < 16; ++r) {
          const int rloc = wr * 128 + mf * 32 + (r & 3) + 8 * (r >> 2) + 4 * kh;
          atomicAdd(&pf[rloc], part[r]);
        }
      }
    }
  }
  if constexpr (EPI == 1) {
    __syncthreads();
    if (tid < 256)
      aux[(long)bx * 8192 + bz * 2048 + by * 256 + tid] = pf[tid];
  }
}

// inv[r] = 1 / sum_k psumG[k][r],  8 col-chunks, 8192 rows
__global__ __launch_bounds__(256)
void invrow(const float* __restrict__ psumG, float* __restrict__ inv) {
  const int r = blockIdx.x * 256 + threadIdx.x;
  float s = 0.f;
#pragma unroll
  for (int k = 0; k < 8; ++k) s += psumG[(long)k * 8192 + r];
  inv[r] = 1.0f / s;
}

// ===========================================================================
// prep: fused conv2 (fp32->bf16 x,y) + wtrans3 (W^T bf16) + bconcat3.
// grid = 8192 (conv) + 3072 (wtrans) + 12 (bias) = 11276 blocks x 256.
// ===========================================================================
__global__ __launch_bounds__(256)
void prep(const float* __restrict__ x, const float* __restrict__ y,
          const float* __restrict__ W0, const float* __restrict__ W1,
          const float* __restrict__ W2,
          const float* __restrict__ b0, const float* __restrict__ b1,
          const float* __restrict__ b2,
          ushort_t* __restrict__ xb, ushort_t* __restrict__ yb,
          ushort_t* __restrict__ Wall, float* __restrict__ bias3)
{
  const int gid = blockIdx.x;
  const int t = threadIdx.x;
  if (gid < 8192) {                         // ---- conv fp32->bf16
    const float* in = (gid < 4096) ? x : y;
    ushort_t* outp = (gid < 4096) ? xb : yb;
    const long i = (long)(gid & 4095) * 256 + t;
    const float4 a = ((const float4*)in)[i * 2];
    const float4 c = ((const float4*)in)[i * 2 + 1];
    uint4 o;
    o.x = (unsigned)f2bf(a.x) | ((unsigned)f2bf(a.y) << 16);
    o.y = (unsigned)f2bf(a.z) | ((unsigned)f2bf(a.w) << 16);
    o.z = (unsigned)f2bf(c.x) | ((unsigned)f2bf(c.y) << 16);
    o.w = (unsigned)f2bf(c.z) | ((unsigned)f2bf(c.w) << 16);
    ((uint4*)outp)[i] = o;
  } else if (gid < 11264) {                 // ---- weight transpose
    const int wgi = gid - 8192;
    const int z = wgi >> 10;
    const int rsub = wgi & 1023;
    const int bx = (rsub & 31) * 32;        // n-tile
    const int by = (rsub >> 5) * 32;        // k-tile
    const float* W = (z == 0) ? W0 : (z == 1) ? W1 : W2;
    ushort_t* Wt = Wall + (long)z * (1024l * 1024);
    __shared__ float tile[32][33];
    const int c = t & 31, r0 = t >> 5;
#pragma unroll
    for (int i = 0; i < 4; ++i)
      tile[r0 + i * 8][c] = W[(long)(by + r0 + i * 8) * 1024 + bx + c];
    __syncthreads();
#pragma unroll
    for (int i = 0; i < 4; ++i)
      Wt[(long)(bx + r0 + i * 8) * 1024 + by + c] = f2bf(tile[c][r0 + i * 8]);
  } else {                                  // ---- bias concat
    const int i = (gid - 11264) * 256 + t;
    if (i < 3072)
      bias3[i] = (i < 1024) ? b0[i] : (i < 2048) ? b1[i - 1024] : b2[i - 2048];
  }
}

extern "C" void kernel_launch(void* const* d_in, const int* in_sizes, int n_in,
                              void* d_out, int out_size, void* d_ws, size_t ws_size,
                              hipStream_t stream) {
  const float* x  = (const float*)d_in[0];
  const float* y  = (const float*)d_in[1];
  const float* Wq = (const float*)d_in[2];
  const float* bq = (const float*)d_in[3];
  const float* Wk = (const float*)d_in[4];
  const float* bk = (const float*)d_in[5];
  const float* Wv = (const float*)d_in[6];
  const float* bv = (const float*)d_in[7];
  float* out = (float*)d_out;

  const int D = 1024;
  const long MB_ = 1l << 20;

  // ws layout (ushort units):
  //  [0,3M)    Wall = Wq^T||Wk^T||Wv^T  [3072][1024] bf16
  //  [3M,27M)  QKV8 [8192][3072] bf16 (Q cols 0-1023, K 1024-2047; V unused)
  //  [27M,43M) Sb [B][2048][2048] bf16; pre-aliased: yb@27M, xb@35M
  //  [43M,51M) Vt [B][1024][2048] bf16  (written by gemm_qkv2 epilogue)
  //  [51M+)    bias3 [3072] f32, psumG [8][8192] f32, inv [8192] f32
  ushort_t* ws   = (ushort_t*)d_ws;
  ushort_t* Wall = ws;
  ushort_t* QKV8 = ws + 3 * MB_;
  ushort_t* Sb   = ws + 27 * MB_;
  ushort_t* yb   = ws + 27 * MB_;
  ushort_t* xb   = ws + 35 * MB_;
  ushort_t* Vt   = ws + 43 * MB_;
  float*    bias3 = (float*)(ws + 51 * MB_);
  float*    psumG = (float*)(ws + 51 * MB_ + 8192);
  float*    inv   = psumG + 8 * 8192;

  dim3 blk(256);

  // fused conversion + weight transpose + bias concat
  prep<<<dim3(11276), blk, 0, stream>>>(
      x, y, Wq, Wk, Wv, bq, bk, bv, xb, yb, Wall, bias3);

  // QKV: Q,K -> QKV8 (ldc 3072); V -> Vt transposed. grid 24x64 = 1536
  gemm_qkv2<<<dim3(1536), blk, 0, stream>>>(xb, yb, Wall, QKV8, Vt, bias3);

  // P' = exp((Q K^T)/32) -> bf16 [B][2048][2048] + row partial sums
  gemm_big<256, 1><<<dim3(256), dim3(512), 0, stream>>>(
      QKV8, QKV8 + 1024, Sb, psumG,
      8, 8, D, 3072, 3072, 2048,
      2048l * 3072, 2048l * 3072, 2048l * 2048, 0.03125f);

  invrow<<<dim3(32), blk, 0, stream>>>(psumG, inv);

  // out = (P' @ V) * inv[row]
  gemm_big<128, 2><<<dim3(256), blk, 0, stream>>>(
      Sb, Vt, out, inv,
      8, 8, 2048, 2048, 2048, D,
      2048l * 2048, 1024l * 2048, 2048l * 1024, 1.0f);
}